// Round 8
// baseline (845.037 us; speedup 1.0000x reference)
//
#include <hip/hip_runtime.h>

#define OUTSZ 524288  // elems per output level (64*32*16*16)
typedef float f4 __attribute__((ext_vector_type(4)));

// ---------------- cubic (Keys a=-0.5), matches jax.image.resize 'cubic' ----
__device__ __forceinline__ float cubic_w(float x) {
    x = fabsf(x);
    if (x >= 2.f) return 0.f;
    if (x >= 1.f) return ((-0.5f * x + 2.5f) * x - 4.f) * x + 2.f;
    return ((1.5f * x - 2.5f) * x) * x + 1.f;
}

template <int PN>
__device__ __forceinline__ void taps(int o, float* w, int& i0, int& n) {
    float sf = (o + 0.5f) * ((float)PN / 16.f) - 0.5f;
    int lo = (int)floorf(sf) - 1;
    int hi = lo + 3;
    if (lo < 0) lo = 0;
    if (hi > PN - 1) hi = PN - 1;
    n = hi - lo + 1;
    i0 = lo;
    float tot = 0.f;
    for (int i = 0; i < n; i++) {
        float ww = cubic_w(sf - (float)(lo + i));
        w[i] = ww;
        tot += ww;
    }
    float inv = 1.f / tot;
    for (int i = 0; i < n; i++) w[i] *= inv;
}

// ---- exact-order helpers (match numpy reference rounding; do not touch) ----
#define FMA4(D, A, B)                                                          \
    D = __builtin_fmaf((A).x, (B).x, D); D = __builtin_fmaf((A).y, (B).y, D);  \
    D = __builtin_fmaf((A).z, (B).z, D); D = __builtin_fmaf((A).w, (B).w, D)
#define DOT32(D)                                                               \
    FMA4(D, z0, w0); FMA4(D, z1, w1); FMA4(D, z2, w2); FMA4(D, z3, w3);        \
    FMA4(D, z4, w4); FMA4(D, z5, w5); FMA4(D, z6, w6); FMA4(D, z7, w7)
#define LOADW(K)                                                               \
    const f4* wr = (const f4*)emb + (size_t)(K) * 8;                           \
    f4 w0 = wr[0], w1 = wr[1], w2 = wr[2], w3 = wr[3];                         \
    f4 w4 = wr[4], w5 = wr[5], w6 = wr[6], w7 = wr[7]

__device__ __forceinline__ float pairwise_zsq(f4 z0, f4 z1, f4 z2, f4 z3,
                                              f4 z4, f4 z5, f4 z6, f4 z7) {
#define SQ_(a) __fmul_rn((a), (a))
#define R4_(a, b, c, d) \
    __fadd_rn(__fadd_rn(__fadd_rn(SQ_(a), SQ_(b)), SQ_(c)), SQ_(d))
    float r0 = R4_(z0.x, z2.x, z4.x, z6.x);
    float r1 = R4_(z0.y, z2.y, z4.y, z6.y);
    float r2 = R4_(z0.z, z2.z, z4.z, z6.z);
    float r3 = R4_(z0.w, z2.w, z4.w, z6.w);
    float r4 = R4_(z1.x, z3.x, z5.x, z7.x);
    float r5 = R4_(z1.y, z3.y, z5.y, z7.y);
    float r6 = R4_(z1.z, z3.z, z5.z, z7.z);
    float r7 = R4_(z1.w, z3.w, z5.w, z7.w);
    return __fadd_rn(__fadd_rn(__fadd_rn(r0, r1), __fadd_rn(r2, r3)),
                     __fadd_rn(__fadd_rn(r4, r5), __fadd_rn(r6, r7)));
#undef R4_
#undef SQ_
}

// ||e_k||^2, exact shfl-tree association (offsets 16..1) from passing rounds
__device__ __forceinline__ float wsq_tree(const float* __restrict__ emb, int k) {
    const f4* er = (const f4*)(emb + (size_t)k * 32);
    float a[32];
#pragma unroll
    for (int q = 0; q < 8; q++) {
        f4 v = er[q];
        a[4 * q]     = __fmul_rn(v.x, v.x);
        a[4 * q + 1] = __fmul_rn(v.y, v.y);
        a[4 * q + 2] = __fmul_rn(v.z, v.z);
        a[4 * q + 3] = __fmul_rn(v.w, v.w);
    }
#pragma unroll
    for (int off = 16; off > 0; off >>= 1)
#pragma unroll
        for (int c = 0; c < 16; c++)
            if (c < off) a[c] = __fadd_rn(a[c], a[c + off]);
    return a[0];
}

__device__ __forceinline__ void lexmin(float& bd, int& bi, float d, int i) {
    if (d < bd || (d == bd && i < bi)) { bd = d; bi = i; }
}

#define PINZ asm volatile("" : "+v"(z0), "+v"(z1), "+v"(z2), "+v"(z3),        \
                               "+v"(z4), "+v"(z5), "+v"(z6), "+v"(z7))
#define ZFROM(EXPR)                                                            \
    f4 z0, z1, z2, z3, z4, z5, z6, z7;                                         \
    { float zt_[32];                                                           \
      _Pragma("unroll") for (int c_ = 0; c_ < 32; c_++) zt_[c_] = (EXPR);      \
      z0.x=zt_[0];z0.y=zt_[1];z0.z=zt_[2];z0.w=zt_[3];                         \
      z1.x=zt_[4];z1.y=zt_[5];z1.z=zt_[6];z1.w=zt_[7];                         \
      z2.x=zt_[8];z2.y=zt_[9];z2.z=zt_[10];z2.w=zt_[11];                       \
      z3.x=zt_[12];z3.y=zt_[13];z3.z=zt_[14];z3.w=zt_[15];                     \
      z4.x=zt_[16];z4.y=zt_[17];z4.z=zt_[18];z4.w=zt_[19];                     \
      z5.x=zt_[20];z5.y=zt_[21];z5.z=zt_[22];z5.w=zt_[23];                     \
      z6.x=zt_[24];z6.y=zt_[25];z6.z=zt_[26];z6.w=zt_[27];                     \
      z7.x=zt_[28];z7.y=zt_[29];z7.z=zt_[30];z7.w=zt_[31]; }                   \
    PINZ

// ---------------- K0: wsq + L0 plane means ---------------------------------
__global__ void __launch_bounds__(256) kernel0(
    const float* __restrict__ z_enc, const float* __restrict__ emb,
    float* __restrict__ wsq_g, float* __restrict__ zmean) {
    int bid = blockIdx.x, t = threadIdx.x, lane = t & 63, wv = t >> 6;
    if (bid < 16) { int k = bid * 256 + t; wsq_g[k] = wsq_tree(emb, k); return; }
    int plane = (bid - 16) * 4 + wv;   // 512 blocks x 4 planes = 2048
    float p[4];
#pragma unroll
    for (int s2 = 0; s2 < 4; s2++) {
        float v = z_enc[plane * 256 + s2 * 64 + lane];
        for (int o = 32; o > 0; o >>= 1) v += __shfl_down(v, o, 64);
        p[s2] = v;
    }
    if (lane == 0)
        zmean[plane] = (((p[0] + p[1]) + p[2]) + p[3]) * (1.f / 256.f);
}

// ---------------- P0: L0 full argmin (one block per batch) ------------------
__global__ void __launch_bounds__(256) kernelP0(
    const float* __restrict__ zmean, const float* __restrict__ emb,
    const float* __restrict__ wsq_g, int* __restrict__ ti0) {
    __shared__ float pd[4];
    __shared__ int pi[4];
    int b = blockIdx.x, t = threadIdx.x, lane = t & 63, wv = t >> 6;
    ZFROM(zmean[b * 32 + c_]);
    float zsq = pairwise_zsq(z0, z1, z2, z3, z4, z5, z6, z7);
    float bd = 1e30f; int bi = 0x7fffffff;
#pragma unroll 2
    for (int j = 0; j < 16; j++) {
        int k = j * 256 + t;
        LOADW(k);
        float dot = 0.f; DOT32(dot);
        float d = __fsub_rn(__fadd_rn(zsq, wsq_g[k]), __fadd_rn(dot, dot));
        lexmin(bd, bi, d, k);
    }
    for (int off = 32; off > 0; off >>= 1) {
        float od = __shfl_down(bd, off, 64);
        int oi = __shfl_down(bi, off, 64);
        lexmin(bd, bi, od, oi);
    }
    if (lane == 0) { pd[wv] = bd; pi[wv] = bi; }
    __syncthreads();
    if (t == 0) {
        float b2 = pd[0]; int i2 = pi[0];
        for (int s2 = 1; s2 < 4; s2++) lexmin(b2, i2, pd[s2], pi[s2]);
        ti0[b] = i2;
    }
}

struct ShPA {
    float rest[32 * 257];  // 32.9 KB, bank (c+px)%32
    float zu[64 * 33];     // prev winner rows <-> next tokens
    int   ti[64];
};

// ---------------- PA1: apply L0 + part L1 (grid 64 x 4) ---------------------
__global__ void __launch_bounds__(256) kernelPA1(
    const float* __restrict__ z_enc, const float* __restrict__ emb,
    float* __restrict__ out, float* __restrict__ rA, const int* __restrict__ ti0,
    float* __restrict__ cd1, int* __restrict__ ci1) {
    __shared__ ShPA sh;
    int b = blockIdx.x, s = blockIdx.y, t = threadIdx.x;
    if (t < 32) sh.zu[t] = emb[(size_t)ti0[b] * 32 + t];
    __syncthreads();
    // apply L0 (PN=1): zup = zu[c]
#pragma unroll
    for (int c = 0; c < 32; c++) {
        float zup = sh.zu[c];
        size_t idx = (size_t)b * 8192 + c * 256 + t;
        if (s == 0) out[idx] = __fadd_rn(0.f, zup);
        float rv = __fsub_rn(z_enc[idx], zup);
        if (s == 0) rA[idx] = rv;
        sh.rest[c * 257 + t] = rv;
    }
    __syncthreads();
    if (t < 128) {  // downsample S=8 -> 4 tokens
        int tok = t >> 5, c = t & 31, ii = tok >> 1, jj = tok & 1;
        float acc = 0.f;
        for (int di = 0; di < 8; di++)
            for (int dj = 0; dj < 8; dj++)
                acc = __fadd_rn(acc, sh.rest[c * 257 + (ii * 8 + di) * 16 + (jj * 8 + dj)]);
        sh.zu[tok * 33 + c] = acc * (1.f / 64.f);
    }
    __syncthreads();
    // part L1: wave = token, 64 lanes k-parallel over this block's 1024 codes
    int lane = t & 63, tok = t >> 6;
    ZFROM(sh.zu[tok * 33 + c_]);
    float zsq = pairwise_zsq(z0, z1, z2, z3, z4, z5, z6, z7);
    float bd = 1e30f; int bi = 0x7fffffff;
#pragma unroll 2
    for (int j = 0; j < 16; j++) {
        int k = s * 1024 + j * 64 + lane;
        LOADW(k);
        float dot = 0.f; DOT32(dot);
        float d = __fsub_rn(__fadd_rn(zsq, wsq_tree(emb, k) * 0.f + __ldg(0 ? (const float*)0 : (const float*)0)), 0.f);
        (void)d;  // placeholder removed below
        float dd = __fsub_rn(__fadd_rn(zsq, *(emb - emb + (const float*)0 == 0 ? (const float*)0 : (const float*)0)), 0.f);
        (void)dd;
        lexmin(bd, bi, 1e30f, k);  // overwritten below
    }
    // NOTE: loop rewritten without wsq recompute:
    bd = 1e30f; bi = 0x7fffffff;
    {
        const float* wsq_g = nullptr; (void)wsq_g;
    }
    cd1[(size_t)s * 256 + b * 4 + tok] = bd;
    ci1[(size_t)s * 256 + b * 4 + tok] = bi;
}

extern "C" void kernel_launch(void* const* d_in, const int* in_sizes, int n_in,
                              void* d_out, int out_size, void* d_ws, size_t ws_size,
                              hipStream_t stream);

// ---------------- PA1 (corrected) -------------------------------------------
__global__ void __launch_bounds__(256) kernelPA1b(
    const float* __restrict__ z_enc, const float* __restrict__ emb,
    const float* __restrict__ wsq_g, float* __restrict__ out,
    float* __restrict__ rA, const int* __restrict__ ti0,
    float* __restrict__ cd1, int* __restrict__ ci1) {
    __shared__ ShPA sh;
    int b = blockIdx.x, s = blockIdx.y, t = threadIdx.x;
    if (t < 32) sh.zu[t] = emb[(size_t)ti0[b] * 32 + t];
    __syncthreads();
#pragma unroll
    for (int c = 0; c < 32; c++) {
        float zup = sh.zu[c];
        size_t idx = (size_t)b * 8192 + c * 256 + t;
        if (s == 0) out[idx] = __fadd_rn(0.f, zup);
        float rv = __fsub_rn(z_enc[idx], zup);
        if (s == 0) rA[idx] = rv;
        sh.rest[c * 257 + t] = rv;
    }
    __syncthreads();
    if (t < 128) {
        int tok = t >> 5, c = t & 31, ii = tok >> 1, jj = tok & 1;
        float acc = 0.f;
        for (int di = 0; di < 8; di++)
            for (int dj = 0; dj < 8; dj++)
                acc = __fadd_rn(acc, sh.rest[c * 257 + (ii * 8 + di) * 16 + (jj * 8 + dj)]);
        sh.zu[tok * 33 + c] = acc * (1.f / 64.f);
    }
    __syncthreads();
    int lane = t & 63, tok = t >> 6;
    ZFROM(sh.zu[tok * 33 + c_]);
    float zsq = pairwise_zsq(z0, z1, z2, z3, z4, z5, z6, z7);
    float bd = 1e30f; int bi = 0x7fffffff;
#pragma unroll 2
    for (int j = 0; j < 16; j++) {
        int k = s * 1024 + j * 64 + lane;
        LOADW(k);
        float dot = 0.f; DOT32(dot);
        float d = __fsub_rn(__fadd_rn(zsq, wsq_g[k]), __fadd_rn(dot, dot));
        lexmin(bd, bi, d, k);
    }
    for (int off = 32; off > 0; off >>= 1) {
        float od = __shfl_down(bd, off, 64);
        int oi = __shfl_down(bi, off, 64);
        lexmin(bd, bi, od, oi);
    }
    if (lane == 0) {
        cd1[(size_t)s * 256 + b * 4 + tok] = bd;
        ci1[(size_t)s * 256 + b * 4 + tok] = bi;
    }
}

// ---------------- PA2: combine L1 + apply L1 + part L2 (grid 64 x 8) --------
__global__ void __launch_bounds__(256) kernelPA2(
    const float* __restrict__ emb, const float* __restrict__ wsq_g,
    float* __restrict__ out, const float* __restrict__ rA, float* __restrict__ rB,
    const float* __restrict__ cd1, const int* __restrict__ ci1,
    float* __restrict__ cd2, int* __restrict__ ci2) {
    __shared__ ShPA sh;
    int b = blockIdx.x, s = blockIdx.y, t = threadIdx.x;
    if (t < 4) {
        float bd = 1e30f; int bi = 0x7fffffff;
        for (int s2 = 0; s2 < 4; s2++)
            lexmin(bd, bi, cd1[(size_t)s2 * 256 + b * 4 + t], ci1[(size_t)s2 * 256 + b * 4 + t]);
        sh.ti[t] = bi;
    }
    __syncthreads();
    if (t < 128) sh.zu[(t >> 5) * 33 + (t & 31)] = emb[(size_t)sh.ti[t >> 5] * 32 + (t & 31)];
    __syncthreads();
    {   // apply L1 (PN=2)
        int h = t >> 4, w = t & 15;
        float wy[4], wx[4]; int iy0, ny, jx0, nx;
        taps<2>(h, wy, iy0, ny);
        taps<2>(w, wx, jx0, nx);
#pragma unroll
        for (int c = 0; c < 32; c++) {
            float zup = 0.f;
            for (int e = 0; e < nx; e++) {
                float ca = 0.f;
                for (int a = 0; a < ny; a++)
                    ca += wy[a] * sh.zu[((iy0 + a) * 2 + (jx0 + e)) * 33 + c];
                zup += wx[e] * ca;
            }
            size_t idx = (size_t)b * 8192 + c * 256 + t;
            if (s == 0) out[(size_t)OUTSZ + idx] = __fadd_rn(out[idx], zup);
            float rv = __fsub_rn(rA[idx], zup);
            if (s == 0) rB[idx] = rv;
            sh.rest[c * 257 + t] = rv;
        }
    }
    __syncthreads();
#pragma unroll
    for (int i = 0; i < 2; i++) {  // downsample S=4 -> 16 tokens
        int task = i * 256 + t;
        int tok = task >> 5, c = task & 31, ii = tok >> 2, jj = tok & 3;
        float acc = 0.f;
        for (int di = 0; di < 4; di++)
            for (int dj = 0; dj < 4; dj++)
                acc = __fadd_rn(acc, sh.rest[c * 257 + (ii * 4 + di) * 16 + (jj * 4 + dj)]);
        sh.zu[tok * 33 + c] = acc * (1.f / 16.f);
    }
    __syncthreads();
    // part L2: tok = t>>4, kgrp = t&15; block scans 512 codes
    int tok = t >> 4, kg = t & 15;
    ZFROM(sh.zu[tok * 33 + c_]);
    float zsq = pairwise_zsq(z0, z1, z2, z3, z4, z5, z6, z7);
    float bd = 1e30f; int bi = 0x7fffffff;
#pragma unroll 2
    for (int j = 0; j < 32; j++) {
        int k = s * 512 + kg * 32 + j;
        LOADW(k);
        float dot = 0.f; DOT32(dot);
        float d = __fsub_rn(__fadd_rn(zsq, wsq_g[k]), __fadd_rn(dot, dot));
        lexmin(bd, bi, d, k);
    }
    for (int off = 8; off > 0; off >>= 1) {
        float od = __shfl_down(bd, off, 64);
        int oi = __shfl_down(bi, off, 64);
        lexmin(bd, bi, od, oi);
    }
    if (kg == 0) {
        cd2[(size_t)s * 1024 + b * 16 + tok] = bd;
        ci2[(size_t)s * 1024 + b * 16 + tok] = bi;
    }
}

// ---------------- PA3: combine L2 + apply L2 + part L3 (grid 64 x 16) -------
__global__ void __launch_bounds__(256) kernelPA3(
    const float* __restrict__ emb, const float* __restrict__ wsq_g,
    float* __restrict__ out, const float* __restrict__ rB, float* __restrict__ rA,
    const float* __restrict__ cd2, const int* __restrict__ ci2,
    float* __restrict__ cd3, int* __restrict__ ci3) {
    __shared__ ShPA sh;
    int b = blockIdx.x, s = blockIdx.y, t = threadIdx.x;
    if (t < 16) {
        float bd = 1e30f; int bi = 0x7fffffff;
        for (int s2 = 0; s2 < 8; s2++)
            lexmin(bd, bi, cd2[(size_t)s2 * 1024 + b * 16 + t], ci2[(size_t)s2 * 1024 + b * 16 + t]);
        sh.ti[t] = bi;
    }
    __syncthreads();
#pragma unroll
    for (int i = 0; i < 2; i++) {
        int task = i * 256 + t;
        sh.zu[(task >> 5) * 33 + (task & 31)] = emb[(size_t)sh.ti[task >> 5] * 32 + (task & 31)];
    }
    __syncthreads();
    {   // apply L2 (PN=4)
        int h = t >> 4, w = t & 15;
        float wy[4], wx[4]; int iy0, ny, jx0, nx;
        taps<4>(h, wy, iy0, ny);
        taps<4>(w, wx, jx0, nx);
#pragma unroll
        for (int c = 0; c < 32; c++) {
            float zup = 0.f;
            for (int e = 0; e < nx; e++) {
                float ca = 0.f;
                for (int a = 0; a < ny; a++)
                    ca += wy[a] * sh.zu[((iy0 + a) * 4 + (jx0 + e)) * 33 + c];
                zup += wx[e] * ca;
            }
            size_t idx = (size_t)b * 8192 + c * 256 + t;
            if (s == 0) out[2 * (size_t)OUTSZ + idx] = __fadd_rn(out[(size_t)OUTSZ + idx], zup);
            float rv = __fsub_rn(rB[idx], zup);
            if (s == 0) rA[idx] = rv;
            sh.rest[c * 257 + t] = rv;
        }
    }
    __syncthreads();
#pragma unroll
    for (int i = 0; i < 8; i++) {  // downsample S=2 -> 64 tokens
        int task = i * 256 + t;
        int tok = task >> 5, c = task & 31, ii = tok >> 3, jj = tok & 7;
        float acc = 0.f;
        for (int di = 0; di < 2; di++)
            for (int dj = 0; dj < 2; dj++)
                acc = __fadd_rn(acc, sh.rest[c * 257 + (ii * 2 + di) * 16 + (jj * 2 + dj)]);
        sh.zu[tok * 33 + c] = acc * 0.25f;
    }
    __syncthreads();
    // part L3: tok = t>>2, kgrp = t&3; block scans 256 codes
    int tok = t >> 2, kg = t & 3;
    ZFROM(sh.zu[tok * 33 + c_]);
    float zsq = pairwise_zsq(z0, z1, z2, z3, z4, z5, z6, z7);
    float bd = 1e30f; int bi = 0x7fffffff;
#pragma unroll 2
    for (int j = 0; j < 64; j++) {
        int k = s * 256 + kg * 64 + j;
        LOADW(k);
        float dot = 0.f; DOT32(dot);
        float d = __fsub_rn(__fadd_rn(zsq, wsq_g[k]), __fadd_rn(dot, dot));
        lexmin(bd, bi, d, k);
    }
    for (int off = 2; off > 0; off >>= 1) {
        float od = __shfl_down(bd, off, 64);
        int oi = __shfl_down(bi, off, 64);
        lexmin(bd, bi, od, oi);
    }
    if (kg == 0) {
        cd3[(size_t)s * 4096 + b * 64 + tok] = bd;
        ci3[(size_t)s * 4096 + b * 64 + tok] = bi;
    }
}

// ---------------- PA4: combine L3 + apply L3 + part L4 (grid 64 x 32) -------
__global__ void __launch_bounds__(256, 4) kernelPA4(
    const float* __restrict__ emb, const float* __restrict__ wsq_g,
    float* __restrict__ out, const float* __restrict__ rA,
    const float* __restrict__ cd3, const int* __restrict__ ci3,
    float* __restrict__ cd4, int* __restrict__ ci4) {
    __shared__ float zu[64 * 33];
    __shared__ int ti[64];
    int b = blockIdx.x, s = blockIdx.y, t = threadIdx.x;
    if (t < 64) {
        float bd = 1e30f; int bi = 0x7fffffff;
        for (int s2 = 0; s2 < 16; s2++)
            lexmin(bd, bi, cd3[(size_t)s2 * 4096 + b * 64 + t], ci3[(size_t)s2 * 4096 + b * 64 + t]);
        ti[t] = bi;
    }
    __syncthreads();
#pragma unroll
    for (int i = 0; i < 8; i++) {
        int task = i * 256 + t;
        zu[(task >> 5) * 33 + (task & 31)] = emb[(size_t)ti[task >> 5] * 32 + (task & 31)];
    }
    __syncthreads();
    // apply L3 (PN=8) per pixel; zv = L4 token vector in regs
    int h = t >> 4, w = t & 15;
    float wy[4], wx[4]; int iy0, ny, jx0, nx;
    taps<8>(h, wy, iy0, ny);
    taps<8>(w, wx, jx0, nx);
    float zv[32];
#pragma unroll
    for (int c = 0; c < 32; c++) {
        float zup = 0.f;
        for (int e = 0; e < nx; e++) {
            float ca = 0.f;
            for (int a = 0; a < ny; a++)
                ca += wy[a] * zu[((iy0 + a) * 8 + (jx0 + e)) * 33 + c];
            zup += wx[e] * ca;
        }
        size_t idx = (size_t)b * 8192 + c * 256 + t;
        if (s == 0) out[3 * (size_t)OUTSZ + idx] = __fadd_rn(out[2 * (size_t)OUTSZ + idx], zup);
        zv[c] = __fsub_rn(rA[idx], zup);
    }
    ZFROM(zv[c_]);
    float zsq = pairwise_zsq(z0, z1, z2, z3, z4, z5, z6, z7);
    float bd = 1e30f; int bi = 0x7fffffff;
    int k0 = s * 128;
#pragma unroll 2
    for (int k = k0; k < k0 + 128; k++) {  // wave-uniform -> s_load
        LOADW(k);
        float dot = 0.f; DOT32(dot);
        float d = __fsub_rn(__fadd_rn(zsq, wsq_g[k]), __fadd_rn(dot, dot));
        lexmin(bd, bi, d, k);
    }
    cd4[(size_t)s * 16384 + b * 256 + t] = bd;
    ci4[(size_t)s * 16384 + b * 256 + t] = bi;
}

// ---------------- F: combine L4 + apply (identity upsample) -----------------
__global__ void __launch_bounds__(256) kernelF(
    const float* __restrict__ emb, float* __restrict__ out,
    const float* __restrict__ cd4, const int* __restrict__ ci4) {
    int plane = blockIdx.x;
    int b = plane >> 5, c = plane & 31;
    int t = threadIdx.x;
    int tok = b * 256 + t;
    float bd = 1e30f; int bi = 0x7fffffff;
    for (int s = 0; s < 32; s++)
        lexmin(bd, bi, cd4[(size_t)s * 16384 + tok], ci4[(size_t)s * 16384 + tok]);
    float zup = emb[(size_t)bi * 32 + c];
    size_t idx = (size_t)plane * 256 + t;
    out[4 * (size_t)OUTSZ + idx] = __fadd_rn(out[3 * (size_t)OUTSZ + idx], zup);
}

extern "C" void kernel_launch(void* const* d_in, const int* in_sizes, int n_in,
                              void* d_out, int out_size, void* d_ws, size_t ws_size,
                              hipStream_t stream) {
    const float* z_enc = (const float*)d_in[0];   // [64,32,16,16]
    const float* emb   = (const float*)d_in[1];   // [4096,32]
    float* out = (float*)d_out;                   // [5,64,32,16,16]

    float* wsq_g = (float*)d_ws;                  // 4096
    float* zmean = wsq_g + 4096;                  // 2048
    int*   ti0   = (int*)(zmean + 2048);          // 64
    float* rA    = (float*)(ti0 + 64);            // 524288
    float* rB    = rA + 524288;                   // 524288
    float* cd1   = rB + 524288;                   // 1024
    int*   ci1   = (int*)(cd1 + 1024);            // 1024
    float* cd2   = (float*)(ci1 + 1024);          // 8192
    int*   ci2   = (int*)(cd2 + 8192);            // 8192
    float* cd3   = (float*)(ci2 + 8192);          // 65536
    int*   ci3   = (int*)(cd3 + 65536);           // 65536
    float* cd4   = (float*)(ci3 + 65536);         // 524288
    int*   ci4   = (int*)(cd4 + 524288);          // 524288

    kernel0<<<528, 256, 0, stream>>>(z_enc, emb, wsq_g, zmean);
    kernelP0<<<64, 256, 0, stream>>>(zmean, emb, wsq_g, ti0);
    kernelPA1b<<<dim3(64, 4), 256, 0, stream>>>(z_enc, emb, wsq_g, out, rA, ti0, cd1, ci1);
    kernelPA2<<<dim3(64, 8), 256, 0, stream>>>(emb, wsq_g, out, rA, rB, cd1, ci1, cd2, ci2);
    kernelPA3<<<dim3(64, 16), 256, 0, stream>>>(emb, wsq_g, out, rB, rA, cd2, ci2, cd3, ci3);
    kernelPA4<<<dim3(64, 32), 256, 0, stream>>>(emb, wsq_g, out, rA, cd3, ci3, cd4, ci4);
    kernelF<<<2048, 256, 0, stream>>>(emb, out, cd4, ci4);
}